// Round 1
// baseline (113.881 us; speedup 1.0000x reference)
//
#include <hip/hip_runtime.h>
#include <hip/hip_bf16.h>

// ---------------------------------------------------------------------------
// GCNArchEmbedder on MI355X.
// Algebra: out(r,:) = [ sum_t cnt_t * relu(T[pa_t] + T[pb_t]) ] @ (0.25*W2)
// where T rows are precomputed 128-vectors indexed by (op,op) pairs / init.
// ---------------------------------------------------------------------------

typedef __attribute__((ext_vector_type(8))) short  bhalf8;   // 8 x bf16 bits
typedef __attribute__((ext_vector_type(4))) float  f32x4;
typedef __attribute__((ext_vector_type(2))) unsigned int u32x2;

#define TAB_ROW 132   // padded table row (floats)   -> breaks bank conflicts
#define VROW    136   // padded V-tile row (bf16)    -> breaks bank conflicts

__device__ __forceinline__ unsigned int bf16rne(float x) {
  unsigned int u = __builtin_bit_cast(unsigned int, x);
  return (u + 0x7FFFu + ((u >> 16) & 1u)) >> 16;
}

// ws layout: R (14*128 fp32) at byte 0 ; W2T (128*128 bf16, x0.25, transposed)
// at byte 8192. Total 40960 bytes.

__global__ __launch_bounds__(256) void prep_kernel(
    const float* __restrict__ init_emb,   // 2 x 96
    const float* __restrict__ op_emb,     // 8 x 48 (only rows 0..5 used)
    const float* __restrict__ wx,         // 96 x 48
    const float* __restrict__ xb,         // 48
    const float* __restrict__ w1,         // 48 x 128
    const float* __restrict__ w2,         // 128 x 128
    float* __restrict__ R,                // out: 14 x 128
    unsigned short* __restrict__ w2t)     // out: 128 x 128 bf16
{
  const int tid = threadIdx.x;
  if (blockIdx.x == 1) {
    // W2T[f][k] = bf16(0.25 * W2[k][f])  (writes coalesced)
    for (int idx = tid; idx < 128 * 128; idx += 256) {
      int f = idx >> 7, k = idx & 127;
      w2t[f * 128 + k] = (unsigned short)bf16rne(0.25f * w2[k * 128 + f]);
    }
    return;
  }
  // rows 0..5 : U1'[o]  = xb + op_emb[o] @ Wx[0:48]
  // rows 6..11: U2 [o]  =      op_emb[o] @ Wx[48:96]
  // rows 12,13: y0init[n] = xb + init[n] @ Wx
  __shared__ float U[14][48];
  for (int idx = tid; idx < 14 * 48; idx += 256) {
    int row = idx / 48, k = idx - row * 48;
    float s;
    if (row < 6) {
      s = xb[k];
      for (int j = 0; j < 48; ++j) s += op_emb[row * 48 + j] * wx[j * 48 + k];
    } else if (row < 12) {
      s = 0.f;
      for (int j = 0; j < 48; ++j) s += op_emb[(row - 6) * 48 + j] * wx[(48 + j) * 48 + k];
    } else {
      s = xb[k];
      for (int j = 0; j < 96; ++j) s += init_emb[(row - 12) * 96 + j] * wx[j * 48 + k];
    }
    U[row][k] = s;
  }
  __syncthreads();
  // R[row] = U[row] @ W1   (rows 0..5 = P1', 6..11 = P2, 12..13 = Z)
  for (int idx = tid; idx < 14 * 128; idx += 256) {
    int row = idx >> 7, f = idx & 127;
    float s = 0.f;
    for (int k = 0; k < 48; ++k) s += U[row][k] * w1[k * 128 + f];
    R[idx] = s;
  }
}

__global__ __launch_bounds__(256, 4) void main_kernel(
    const int* __restrict__ archs,            // 65536 rows x 16 ints
    const float* __restrict__ R,              // 14 x 128
    const unsigned short* __restrict__ w2t,   // 128 x 128 bf16 (x0.25, W2^T)
    float* __restrict__ out)                  // 65536 x 128 fp32
{
  __shared__ float          sT[38 * TAB_ROW];   // 36 (o1,o2) combos + Z0 + Z1
  __shared__ unsigned short sV[64 * VROW];      // V tile, bf16, wave-private 16-row slabs

  const int tid = threadIdx.x;

  // ---- build T table: T[o1*6+o2] = P1'[o1] + P2[o2] ; rows 36,37 = Z0,Z1 ----
  for (int idx = tid; idx < 38 * 128; idx += 256) {
    int row = idx >> 7, f = idx & 127;
    float v;
    if (row < 36) {
      int o1 = row / 6, o2 = row - o1 * 6;
      v = R[o1 * 128 + f] + R[(6 + o2) * 128 + f];
    } else {
      v = R[(row - 24) * 128 + f];   // 36 -> R[12], 37 -> R[13]
    }
    sT[row * TAB_ROW + f] = v;
  }
  __syncthreads();

  const int lane  = tid & 63;
  const int wv    = tid >> 6;                  // wave 0..3
  const int rbase = blockIdx.x * 64 + wv * 16; // this wave's 16 rows

  // ---- phase A: lanes = 16 rows x 4 sub-chunks; 8 iters of 4 dims each ----
  const int rowi = lane >> 2;      // 0..15
  const int sub  = lane & 3;       // 0..3
  const int r    = rbase + rowi;

  const int* ar = archs + r * 16;
  int4 pv0 = *(const int4*)(ar);        // prev[0..3]
  int4 pv1 = *(const int4*)(ar + 4);    // prev[4..7]
  int4 op0 = *(const int4*)(ar + 8);    // op[0..3]
  int4 op1 = *(const int4*)(ar + 12);   // op[4..7]

  int soff0 = (op0.x * 6 + op0.y) * TAB_ROW;
  int soff1 = (op0.z * 6 + op0.w) * TAB_ROW;
  int soff2 = (op1.x * 6 + op1.y) * TAB_ROW;
  int soff3 = (op1.z * 6 + op1.w) * TAB_ROW;
  const int s36 = 36 * TAB_ROW, s37 = 37 * TAB_ROW;

  int prev[8] = {pv0.x, pv0.y, pv0.z, pv0.w, pv1.x, pv1.y, pv1.z, pv1.w};
  int aoff[4], boff[4];
  float cf[4];
#pragma unroll
  for (int t = 0; t < 4; ++t) {
    int pa = prev[2 * t], pb = prev[2 * t + 1];
    aoff[t] = (pa == 0) ? s36 : (pa == 1) ? s37 : (pa == 2) ? soff0
            : (pa == 3) ? soff1 : (pa == 4) ? soff2 : soff3;
    boff[t] = (pb == 0) ? s36 : (pb == 1) ? s37 : (pb == 2) ? soff0
            : (pb == 3) ? soff1 : (pb == 4) ? soff2 : soff3;
    int c = 0;
#pragma unroll
    for (int e = 0; e < 8; ++e) c += (prev[e] == t + 2) ? 1 : 0;
    cf[t] = (float)c;
  }

  const int vwbase = (wv * 16 + rowi) * VROW + sub * 4;
#pragma unroll
  for (int it = 0; it < 8; ++it) {
    const int d = sub * 4 + it * 16;
    f32x4 v = {0.f, 0.f, 0.f, 0.f};
#pragma unroll
    for (int t = 0; t < 4; ++t) {
      f32x4 a = *(const f32x4*)&sT[aoff[t] + d];
      f32x4 b = *(const f32x4*)&sT[boff[t] + d];
      f32x4 y = a + b;
      y[0] = fmaxf(y[0], 0.f); y[1] = fmaxf(y[1], 0.f);
      y[2] = fmaxf(y[2], 0.f); y[3] = fmaxf(y[3], 0.f);
      v += cf[t] * y;
    }
    u32x2 p;
    p[0] = bf16rne(v[0]) | (bf16rne(v[1]) << 16);
    p[1] = bf16rne(v[2]) | (bf16rne(v[3]) << 16);
    *(u32x2*)&sV[vwbase + it * 16] = p;
  }

  // wave-private V slab: only need this wave's LDS writes visible to itself
  asm volatile("s_waitcnt lgkmcnt(0)" ::: "memory");

  // ---- phase B: 16x128 output tile via mfma_f32_16x16x32_bf16 ----
  const int mrow = lane & 15;     // A row / B col / D col
  const int kq   = lane >> 4;     // k-quad

  const unsigned short* vb = &sV[(wv * 16 + mrow) * VROW + kq * 8];
  bhalf8 Af[4];
#pragma unroll
  for (int kc = 0; kc < 4; ++kc) Af[kc] = *(const bhalf8*)(vb + kc * 32);

#pragma unroll
  for (int nt = 0; nt < 8; ++nt) {
    f32x4 acc = {0.f, 0.f, 0.f, 0.f};
    const unsigned short* wb = w2t + (nt * 16 + mrow) * 128 + kq * 8;
#pragma unroll
    for (int kc = 0; kc < 4; ++kc) {
      bhalf8 Bf = *(const bhalf8*)(wb + kc * 32);
      acc = __builtin_amdgcn_mfma_f32_16x16x32_bf16(Af[kc], Bf, acc, 0, 0, 0);
    }
#pragma unroll
    for (int j = 0; j < 4; ++j)
      out[(rbase + kq * 4 + j) * 128 + nt * 16 + mrow] = acc[j];
  }
}

extern "C" void kernel_launch(void* const* d_in, const int* in_sizes, int n_in,
                              void* d_out, int out_size, void* d_ws, size_t ws_size,
                              hipStream_t stream) {
  const int*   archs  = (const int*)d_in[0];
  const float* init_e = (const float*)d_in[1];
  const float* op_e   = (const float*)d_in[2];
  const float* wx     = (const float*)d_in[3];
  const float* xb     = (const float*)d_in[4];
  const float* w1     = (const float*)d_in[5];
  const float* w2     = (const float*)d_in[6];

  float*          R   = (float*)d_ws;
  unsigned short* w2t = (unsigned short*)((char*)d_ws + 8192);

  prep_kernel<<<2, 256, 0, stream>>>(init_e, op_e, wx, xb, w1, w2, R, w2t);
  main_kernel<<<1024, 256, 0, stream>>>(archs, R, w2t, (float*)d_out);
}

// Round 2
// 111.920 us; speedup vs baseline: 1.0175x; 1.0175x over previous
//
#include <hip/hip_runtime.h>
#include <hip/hip_bf16.h>

// ---------------------------------------------------------------------------
// GCNArchEmbedder on MI355X.
// Algebra: out(r,:) = [ sum_t cnt_t * relu(T[pa_t] + T[pb_t]) ] @ (0.25*W2)
// where T rows are precomputed 128-vectors indexed by (op,op) pairs / init.
// ---------------------------------------------------------------------------

typedef __attribute__((ext_vector_type(8))) short  bhalf8;   // 8 x bf16 bits
typedef __attribute__((ext_vector_type(4))) float  f32x4;
typedef __attribute__((ext_vector_type(2))) unsigned int u32x2;

#define TAB_ROW 132   // padded table row (floats)   -> breaks bank conflicts
#define VROW    136   // padded V-tile row (bf16)    -> breaks bank conflicts

__device__ __forceinline__ unsigned int bf16rne(float x) {
  unsigned int u = __builtin_bit_cast(unsigned int, x);
  return (u + 0x7FFFu + ((u >> 16) & 1u)) >> 16;
}

// ws layout: R (14*128 fp32) at byte 0 ; W2T (128*128 bf16, x0.25, transposed)
// at byte 8192. Total 40960 bytes.

__global__ __launch_bounds__(256) void prep_kernel(
    const float* __restrict__ init_emb,   // 2 x 96
    const float* __restrict__ op_emb,     // 8 x 48 (only rows 0..5 used)
    const float* __restrict__ wx,         // 96 x 48
    const float* __restrict__ xb,         // 48
    const float* __restrict__ w1,         // 48 x 128
    const float* __restrict__ w2,         // 128 x 128
    float* __restrict__ R,                // out: 14 x 128
    unsigned short* __restrict__ w2t)     // out: 128 x 128 bf16
{
  const int tid = threadIdx.x;
  const int b = blockIdx.x;

  if (b < 8) {
    // blocks 0..7: W2T[f][k] = bf16(0.25 * W2[k][f]); block b owns f in
    // [16b, 16b+16). Writes coalesced (128B/wave); reads are stride-512B but
    // L2-resident (w2 = 64 KB total).
    const int fbase = b * 16;
#pragma unroll
    for (int i = 0; i < 8; ++i) {
      int idx = i * 256 + tid;          // 0..2047
      int fi = idx >> 7, k = idx & 127;
      int f = fbase + fi;
      w2t[f * 128 + k] = (unsigned short)bf16rne(0.25f * w2[k * 128 + f]);
    }
    return;
  }

  // block 8: R. Stage all small weights into LDS (coalesced), compute there.
  __shared__ float swx[96 * 48];    // 18 KB
  __shared__ float sw1[48 * 128];   // 24 KB
  __shared__ float smisc[6 * 48 + 2 * 96 + 48];
  __shared__ float sU[14][48];

  for (int i = tid; i < 96 * 48; i += 256) swx[i] = wx[i];
  for (int i = tid; i < 48 * 128; i += 256) sw1[i] = w1[i];
  for (int i = tid; i < 288; i += 256) smisc[i] = op_emb[i];          // rows 0..5
  if (tid < 192) smisc[288 + tid] = init_emb[tid];
  if (tid < 48)  smisc[480 + tid] = xb[tid];
  __syncthreads();

  const float* sob   = smisc;
  const float* sinit = smisc + 288;
  const float* sxb   = smisc + 480;

  // rows 0..5 : U1'[o]  = xb + op_emb[o] @ Wx[0:48]
  // rows 6..11: U2 [o]  =      op_emb[o] @ Wx[48:96]
  // rows 12,13: y0init[n] = xb + init[n] @ Wx
  for (int idx = tid; idx < 14 * 48; idx += 256) {
    int row = idx / 48, k = idx - row * 48;
    float s;
    if (row < 6) {
      s = sxb[k];
      for (int j = 0; j < 48; ++j) s += sob[row * 48 + j] * swx[j * 48 + k];
    } else if (row < 12) {
      s = 0.f;
      for (int j = 0; j < 48; ++j) s += sob[(row - 6) * 48 + j] * swx[(48 + j) * 48 + k];
    } else {
      s = sxb[k];
      for (int j = 0; j < 96; ++j) s += sinit[(row - 12) * 96 + j] * swx[j * 48 + k];
    }
    sU[row][k] = s;
  }
  __syncthreads();

  // R[row] = U[row] @ W1   (rows 0..5 = P1', 6..11 = P2, 12..13 = Z)
  for (int idx = tid; idx < 14 * 128; idx += 256) {
    int row = idx >> 7, f = idx & 127;
    float s = 0.f;
    for (int k = 0; k < 48; ++k) s += sU[row][k] * sw1[k * 128 + f];
    R[idx] = s;
  }
}

__global__ __launch_bounds__(256, 4) void main_kernel(
    const int* __restrict__ archs,            // 65536 rows x 16 ints
    const float* __restrict__ R,              // 14 x 128
    const unsigned short* __restrict__ w2t,   // 128 x 128 bf16 (x0.25, W2^T)
    float* __restrict__ out)                  // 65536 x 128 fp32
{
  __shared__ float          sT[38 * TAB_ROW];   // 36 (o1,o2) combos + Z0 + Z1
  __shared__ unsigned short sV[64 * VROW];      // V tile, bf16, wave-private 16-row slabs

  const int tid = threadIdx.x;

  // ---- build T table: T[o1*6+o2] = P1'[o1] + P2[o2] ; rows 36,37 = Z0,Z1 ----
  for (int idx = tid; idx < 38 * 128; idx += 256) {
    int row = idx >> 7, f = idx & 127;
    float v;
    if (row < 36) {
      int o1 = row / 6, o2 = row - o1 * 6;
      v = R[o1 * 128 + f] + R[(6 + o2) * 128 + f];
    } else {
      v = R[(row - 24) * 128 + f];   // 36 -> R[12], 37 -> R[13]
    }
    sT[row * TAB_ROW + f] = v;
  }
  __syncthreads();

  const int lane  = tid & 63;
  const int wv    = tid >> 6;                  // wave 0..3
  const int rbase = blockIdx.x * 64 + wv * 16; // this wave's 16 rows

  // ---- phase A: lanes = 16 rows x 4 sub-chunks; 8 iters of 4 dims each ----
  const int rowi = lane >> 2;      // 0..15
  const int sub  = lane & 3;       // 0..3
  const int r    = rbase + rowi;

  const int* ar = archs + r * 16;
  int4 pv0 = *(const int4*)(ar);        // prev[0..3]
  int4 pv1 = *(const int4*)(ar + 4);    // prev[4..7]
  int4 op0 = *(const int4*)(ar + 8);    // op[0..3]
  int4 op1 = *(const int4*)(ar + 12);   // op[4..7]

  int soff0 = (op0.x * 6 + op0.y) * TAB_ROW;
  int soff1 = (op0.z * 6 + op0.w) * TAB_ROW;
  int soff2 = (op1.x * 6 + op1.y) * TAB_ROW;
  int soff3 = (op1.z * 6 + op1.w) * TAB_ROW;
  const int s36 = 36 * TAB_ROW, s37 = 37 * TAB_ROW;

  int prev[8] = {pv0.x, pv0.y, pv0.z, pv0.w, pv1.x, pv1.y, pv1.z, pv1.w};
  int aoff[4], boff[4];
  float cf[4];
#pragma unroll
  for (int t = 0; t < 4; ++t) {
    int pa = prev[2 * t], pb = prev[2 * t + 1];
    aoff[t] = (pa == 0) ? s36 : (pa == 1) ? s37 : (pa == 2) ? soff0
            : (pa == 3) ? soff1 : (pa == 4) ? soff2 : soff3;
    boff[t] = (pb == 0) ? s36 : (pb == 1) ? s37 : (pb == 2) ? soff0
            : (pb == 3) ? soff1 : (pb == 4) ? soff2 : soff3;
    int c = 0;
#pragma unroll
    for (int e = 0; e < 8; ++e) c += (prev[e] == t + 2) ? 1 : 0;
    cf[t] = (float)c;
  }

  const int vwbase = (wv * 16 + rowi) * VROW + sub * 4;
#pragma unroll
  for (int it = 0; it < 8; ++it) {
    const int d = sub * 4 + it * 16;
    f32x4 v = {0.f, 0.f, 0.f, 0.f};
#pragma unroll
    for (int t = 0; t < 4; ++t) {
      f32x4 a = *(const f32x4*)&sT[aoff[t] + d];
      f32x4 b = *(const f32x4*)&sT[boff[t] + d];
      f32x4 y = a + b;
      y[0] = fmaxf(y[0], 0.f); y[1] = fmaxf(y[1], 0.f);
      y[2] = fmaxf(y[2], 0.f); y[3] = fmaxf(y[3], 0.f);
      v += cf[t] * y;
    }
    u32x2 p;
    p[0] = bf16rne(v[0]) | (bf16rne(v[1]) << 16);
    p[1] = bf16rne(v[2]) | (bf16rne(v[3]) << 16);
    *(u32x2*)&sV[vwbase + it * 16] = p;
  }

  // wave-private V slab: only need this wave's LDS writes visible to itself
  asm volatile("s_waitcnt lgkmcnt(0)" ::: "memory");

  // ---- phase B: 16x128 output tile via mfma_f32_16x16x32_bf16 ----
  const int mrow = lane & 15;     // A row / B col / D col
  const int kq   = lane >> 4;     // k-quad

  const unsigned short* vb = &sV[(wv * 16 + mrow) * VROW + kq * 8];
  bhalf8 Af[4];
#pragma unroll
  for (int kc = 0; kc < 4; ++kc) Af[kc] = *(const bhalf8*)(vb + kc * 32);

#pragma unroll
  for (int nt = 0; nt < 8; ++nt) {
    f32x4 acc = {0.f, 0.f, 0.f, 0.f};
    const unsigned short* wb = w2t + (nt * 16 + mrow) * 128 + kq * 8;
#pragma unroll
    for (int kc = 0; kc < 4; ++kc) {
      bhalf8 Bf = *(const bhalf8*)(wb + kc * 32);
      acc = __builtin_amdgcn_mfma_f32_16x16x32_bf16(Af[kc], Bf, acc, 0, 0, 0);
    }
#pragma unroll
    for (int j = 0; j < 4; ++j)
      out[(rbase + kq * 4 + j) * 128 + nt * 16 + mrow] = acc[j];
  }
}

extern "C" void kernel_launch(void* const* d_in, const int* in_sizes, int n_in,
                              void* d_out, int out_size, void* d_ws, size_t ws_size,
                              hipStream_t stream) {
  const int*   archs  = (const int*)d_in[0];
  const float* init_e = (const float*)d_in[1];
  const float* op_e   = (const float*)d_in[2];
  const float* wx     = (const float*)d_in[3];
  const float* xb     = (const float*)d_in[4];
  const float* w1     = (const float*)d_in[5];
  const float* w2     = (const float*)d_in[6];

  float*          R   = (float*)d_ws;
  unsigned short* w2t = (unsigned short*)((char*)d_ws + 8192);

  prep_kernel<<<9, 256, 0, stream>>>(init_e, op_e, wx, xb, w1, w2, R, w2t);
  main_kernel<<<1024, 256, 0, stream>>>(archs, R, w2t, (float*)d_out);
}

// Round 3
// 108.997 us; speedup vs baseline: 1.0448x; 1.0268x over previous
//
#include <hip/hip_runtime.h>
#include <hip/hip_bf16.h>

// ---------------------------------------------------------------------------
// GCNArchEmbedder on MI355X.
// Algebra: out(r,:) = [ sum_t cnt_t * relu(T[pa_t] + T[pb_t]) ] @ (0.25*W2)
// where T rows are precomputed 128-vectors indexed by (op,op) pairs / init.
// Phase A computes each lane's MFMA A-fragment dims directly in registers
// (no LDS V bounce); phase B does 32x mfma_16x16x32_bf16 against W2T.
// ---------------------------------------------------------------------------

typedef __attribute__((ext_vector_type(8))) short  bhalf8;   // 8 x bf16 bits
typedef __attribute__((ext_vector_type(4))) float  f32x4;

#define TAB_ROW 132   // padded table row (floats) -> spreads bank alignments

__device__ __forceinline__ unsigned int bf16rne(float x) {
  unsigned int u = __builtin_bit_cast(unsigned int, x);
  return (u + 0x7FFFu + ((u >> 16) & 1u)) >> 16;
}

// ws layout: R (14*128 fp32) at byte 0 ; W2T (128*128 bf16, x0.25, transposed)
// at byte 8192. Total 40960 bytes.

__global__ __launch_bounds__(256) void prep_kernel(
    const float* __restrict__ init_emb,   // 2 x 96
    const float* __restrict__ op_emb,     // 8 x 48 (only rows 0..5 used)
    const float* __restrict__ wx,         // 96 x 48
    const float* __restrict__ xb,         // 48
    const float* __restrict__ w1,         // 48 x 128
    const float* __restrict__ w2,         // 128 x 128
    float* __restrict__ R,                // out: 14 x 128
    unsigned short* __restrict__ w2t)     // out: 128 x 128 bf16
{
  const int tid = threadIdx.x;
  const int b = blockIdx.x;

  if (b < 64) {
    // blocks 0..63: W2T[f][k] = bf16(0.25 * W2[k][f]); block b owns f in
    // [2b, 2b+2). 256 elems/block, writes coalesced, reads L2-resident.
    int idx = b * 256 + tid;           // 0..16383
    int f = idx >> 7, k = idx & 127;
    w2t[f * 128 + k] = (unsigned short)bf16rne(0.25f * w2[k * 128 + f]);
    return;
  }

  // block 64: R. Stage all small weights into LDS (coalesced), compute there.
  __shared__ float swx[96 * 48];    // 18 KB
  __shared__ float sw1[48 * 128];   // 24 KB
  __shared__ float smisc[6 * 48 + 2 * 96 + 48];
  __shared__ float sU[14][48];

  for (int i = tid; i < 96 * 48; i += 256) swx[i] = wx[i];
  for (int i = tid; i < 48 * 128; i += 256) sw1[i] = w1[i];
  for (int i = tid; i < 288; i += 256) smisc[i] = op_emb[i];          // rows 0..5
  if (tid < 192) smisc[288 + tid] = init_emb[tid];
  if (tid < 48)  smisc[480 + tid] = xb[tid];
  __syncthreads();

  const float* sob   = smisc;
  const float* sinit = smisc + 288;
  const float* sxb   = smisc + 480;

  // rows 0..5 : U1'[o]  = xb + op_emb[o] @ Wx[0:48]
  // rows 6..11: U2 [o]  =      op_emb[o] @ Wx[48:96]
  // rows 12,13: y0init[n] = xb + init[n] @ Wx
  for (int idx = tid; idx < 14 * 48; idx += 256) {
    int row = idx / 48, k = idx - row * 48;
    float s;
    if (row < 6) {
      s = sxb[k];
      for (int j = 0; j < 48; ++j) s += sob[row * 48 + j] * swx[j * 48 + k];
    } else if (row < 12) {
      s = 0.f;
      for (int j = 0; j < 48; ++j) s += sob[(row - 6) * 48 + j] * swx[(48 + j) * 48 + k];
    } else {
      s = sxb[k];
      for (int j = 0; j < 96; ++j) s += sinit[(row - 12) * 96 + j] * swx[j * 48 + k];
    }
    sU[row][k] = s;
  }
  __syncthreads();

  // R[row] = U[row] @ W1   (rows 0..5 = P1', 6..11 = P2, 12..13 = Z)
  for (int idx = tid; idx < 14 * 128; idx += 256) {
    int row = idx >> 7, f = idx & 127;
    float s = 0.f;
    for (int k = 0; k < 48; ++k) s += sU[row][k] * sw1[k * 128 + f];
    R[idx] = s;
  }
}

__global__ __launch_bounds__(256, 4) void main_kernel(
    const int* __restrict__ archs,            // 65536 rows x 16 ints
    const float* __restrict__ R,              // 14 x 128
    const unsigned short* __restrict__ w2t,   // 128 x 128 bf16 (x0.25, W2^T)
    float* __restrict__ out)                  // 65536 x 128 fp32
{
  __shared__ float sT[38 * TAB_ROW];   // 36 (o1,o2) combos + Z0 + Z1  (20 KB)

  const int tid  = threadIdx.x;
  const int lane = tid & 63;
  const int wv   = tid >> 6;                   // wave 0..3
  const int rbase = blockIdx.x * 64 + wv * 16; // this wave's 16 rows

  // Lane roles (MFMA 16x16x32 A-frag native): m-row and k-quad.
  const int mrow = lane & 15;     // A row / B col / D col
  const int kq   = lane >> 4;     // k-quad: lane holds k = kq*8 + kc*32 + [0..8)
  const int r    = rbase + mrow;

  // ---- prefetch archs early (HBM latency hides behind sT build) ----
  const int* ar = archs + r * 16;
  int4 pv0 = *(const int4*)(ar);        // prev[0..3]
  int4 pv1 = *(const int4*)(ar + 4);    // prev[4..7]
  int4 op0 = *(const int4*)(ar + 8);    // op[0..3]
  int4 op1 = *(const int4*)(ar + 12);   // op[4..7]

  // ---- build T table: T[o1*6+o2] = P1'[o1] + P2[o2] ; rows 36,37 = Z0,Z1 ----
  for (int idx = tid; idx < 38 * 128; idx += 256) {
    int row = idx >> 7, f = idx & 127;
    float v;
    if (row < 36) {
      int o1 = row / 6, o2 = row - o1 * 6;
      v = R[o1 * 128 + f] + R[(6 + o2) * 128 + f];
    } else {
      v = R[(row - 24) * 128 + f];   // 36 -> R[12], 37 -> R[13]
    }
    sT[row * TAB_ROW + f] = v;
  }
  __syncthreads();

  int soff0 = (op0.x * 6 + op0.y) * TAB_ROW;
  int soff1 = (op0.z * 6 + op0.w) * TAB_ROW;
  int soff2 = (op1.x * 6 + op1.y) * TAB_ROW;
  int soff3 = (op1.z * 6 + op1.w) * TAB_ROW;
  const int s36 = 36 * TAB_ROW, s37 = 37 * TAB_ROW;

  int prev[8] = {pv0.x, pv0.y, pv0.z, pv0.w, pv1.x, pv1.y, pv1.z, pv1.w};
  int aoff[4], boff[4];
  float cf[4];
#pragma unroll
  for (int t = 0; t < 4; ++t) {
    int pa = prev[2 * t], pb = prev[2 * t + 1];
    aoff[t] = (pa == 0) ? s36 : (pa == 1) ? s37 : (pa == 2) ? soff0
            : (pa == 3) ? soff1 : (pa == 4) ? soff2 : soff3;
    boff[t] = (pb == 0) ? s36 : (pb == 1) ? s37 : (pb == 2) ? soff0
            : (pb == 3) ? soff1 : (pb == 4) ? soff2 : soff3;
    int c = 0;
#pragma unroll
    for (int e = 0; e < 8; ++e) c += (prev[e] == t + 2) ? 1 : 0;
    cf[t] = (float)c;
  }

  // ---- phase A: compute this lane's A-fragments directly in registers ----
  // Af[kc] holds bf16 of v[k] for k = kq*8 + kc*32 + [0..8).
  bhalf8 Af[4];
#pragma unroll
  for (int kc = 0; kc < 4; ++kc) {
    const int d = kq * 8 + kc * 32;
    unsigned int pk[4];
#pragma unroll
    for (int half = 0; half < 2; ++half) {
      f32x4 v = {0.f, 0.f, 0.f, 0.f};
      const int dd = d + half * 4;
#pragma unroll
      for (int t = 0; t < 4; ++t) {
        f32x4 a = *(const f32x4*)&sT[aoff[t] + dd];
        f32x4 b = *(const f32x4*)&sT[boff[t] + dd];
        f32x4 y = a + b;
        y[0] = fmaxf(y[0], 0.f); y[1] = fmaxf(y[1], 0.f);
        y[2] = fmaxf(y[2], 0.f); y[3] = fmaxf(y[3], 0.f);
        v += cf[t] * y;
      }
      pk[2 * half]     = bf16rne(v[0]) | (bf16rne(v[1]) << 16);
      pk[2 * half + 1] = bf16rne(v[2]) | (bf16rne(v[3]) << 16);
    }
    Af[kc] = __builtin_bit_cast(bhalf8, *(__attribute__((ext_vector_type(4))) unsigned int*)pk);
  }

  // ---- phase B: 16x128 output tile via mfma_f32_16x16x32_bf16 ----
#pragma unroll
  for (int nt = 0; nt < 8; ++nt) {
    f32x4 acc = {0.f, 0.f, 0.f, 0.f};
    const unsigned short* wb = w2t + (nt * 16 + mrow) * 128 + kq * 8;
#pragma unroll
    for (int kc = 0; kc < 4; ++kc) {
      bhalf8 Bf = *(const bhalf8*)(wb + kc * 32);
      acc = __builtin_amdgcn_mfma_f32_16x16x32_bf16(Af[kc], Bf, acc, 0, 0, 0);
    }
#pragma unroll
    for (int j = 0; j < 4; ++j)
      out[(rbase + kq * 4 + j) * 128 + nt * 16 + mrow] = acc[j];
  }
}

extern "C" void kernel_launch(void* const* d_in, const int* in_sizes, int n_in,
                              void* d_out, int out_size, void* d_ws, size_t ws_size,
                              hipStream_t stream) {
  const int*   archs  = (const int*)d_in[0];
  const float* init_e = (const float*)d_in[1];
  const float* op_e   = (const float*)d_in[2];
  const float* wx     = (const float*)d_in[3];
  const float* xb     = (const float*)d_in[4];
  const float* w1     = (const float*)d_in[5];
  const float* w2     = (const float*)d_in[6];

  float*          R   = (float*)d_ws;
  unsigned short* w2t = (unsigned short*)((char*)d_ws + 8192);

  prep_kernel<<<65, 256, 0, stream>>>(init_e, op_e, wx, xb, w1, w2, R, w2t);
  main_kernel<<<1024, 256, 0, stream>>>(archs, R, w2t, (float*)d_out);
}